// Round 19
// baseline (207.313 us; speedup 1.0000x reference)
//
#include <hip/hip_runtime.h>
#include <cstdint>
#include <cstddef>

namespace {

constexpr int NN = 100000;   // nodes
constexpr int NE = 1600000;  // edges
constexpr int DI = 256;
constexpr int DH = 128;
constexpr int DO = 64;
constexpr int EPB = 1024;                     // edges per bucket-hist block
constexpr int NBA = (NE + EPB - 1) / EPB;     // 1563
constexpr int NBUK = (NN + 255) / 256;        // 391 buckets of 256 rows
constexpr int EDOT_NB = NE / 256;   // 6250
constexpr int SP3_NB = NN / 32;     // 3125
constexpr int G1_NB = (NN + 127) / 128;  // 782 gemm blocks
constexpr int G1H = G1_NB / 2;           // 391 per half
constexpr int PREP_NB = (DI * DH + DH * DO) / 256;  // 160

using bf16x8 = __attribute__((ext_vector_type(8))) short;  // 8 bf16 = 4 VGPR
using f32x4  = __attribute__((ext_vector_type(4))) float;

__device__ inline unsigned short f2bf(float f) {
  unsigned int u = __float_as_uint(f);
  u += 0x7FFFu + ((u >> 16) & 1u);  // round-to-nearest-even
  return (unsigned short)(u >> 16);
}
__device__ inline float bflo(unsigned int u) { return __uint_as_float(u << 16); }
__device__ inline float bfhi(unsigned int u) { return __uint_as_float(u & 0xffff0000u); }

__device__ inline void fma8(float* acc, const uint4 g, const float v) {
  acc[0] = fmaf(v, bflo(g.x), acc[0]); acc[1] = fmaf(v, bfhi(g.x), acc[1]);
  acc[2] = fmaf(v, bflo(g.y), acc[2]); acc[3] = fmaf(v, bfhi(g.y), acc[3]);
  acc[4] = fmaf(v, bflo(g.z), acc[4]); acc[5] = fmaf(v, bfhi(g.z), acc[5]);
  acc[6] = fmaf(v, bflo(g.w), acc[6]); acc[7] = fmaf(v, bfhi(g.w), acc[7]);
}

// async global->LDS, 16B per lane; LDS dest = wave-uniform base + lane*16
__device__ __forceinline__ void gl16(const void* g, void* l) {
  __builtin_amdgcn_global_load_lds(
      (const __attribute__((address_space(1))) void*)g,
      (__attribute__((address_space(3))) void*)l, 16, 0, 0);
}

__device__ __forceinline__ bf16x8 pack8(const f32x4 lo, const f32x4 hi) {
  bf16x8 r;
  r[0] = (short)f2bf(lo[0]); r[1] = (short)f2bf(lo[1]);
  r[2] = (short)f2bf(lo[2]); r[3] = (short)f2bf(lo[3]);
  r[4] = (short)f2bf(hi[0]); r[5] = (short)f2bf(hi[1]);
  r[6] = (short)f2bf(hi[2]); r[7] = (short)f2bf(hi[3]);
  return r;
}

// ---- MFMA GEMM block body: gload_lds staging, swizzle masks clamped
// per-operand, EP-pass epilogue. (round-13 verified structure) ----
template <int BM, int BN, int BK, bool ABF16>
__device__ __forceinline__ void gemm_block(const void* __restrict__ Ap,
                                           const unsigned short* __restrict__ Bt,
                                           unsigned short* __restrict__ C,
                                           int M, int K, int bx) {
  constexpr int ABYT = ABF16 ? 2 : 4;
  constexpr int SBA = BK * ABYT;
  constexpr int SBB = BK * 2;
  constexpr int ASZ = BM * SBA;
  constexpr int BSZ = BN * SBB;
  constexpr int STAGE = ASZ + BSZ;
  constexpr int OUTP = BN + 8;
  constexpr int EP = (BM * OUTP * 2 > STAGE) ? 2 : 1;
  constexpr int ROWS_P = BM / EP;
  constexpr int OUTB = ROWS_P * OUTP * 2;
  constexpr int LDSB = STAGE > OUTB ? STAGE : OUTB;
  constexpr int AMSK = (SBA / 16 - 1) > 7 ? 7 : (SBA / 16 - 1);
  constexpr int BMSK = (SBB / 16 - 1) > 7 ? 7 : (SBB / 16 - 1);
  __shared__ __align__(16) char lds[LDSB];
  char* const as_ = lds;
  char* const bs_ = lds + ASZ;

  const int tid = threadIdx.x;
  const int wid = tid >> 6;
  const int lane = tid & 63;
  const int l15 = lane & 15;
  const int lg = lane >> 4;
  const int amsk = (l15 & AMSK) << 4;
  const int bmsk = (l15 & BMSK) << 4;
  const int row0 = bx * BM;

  constexpr int NGA = ASZ / (256 * 16);
  constexpr int NGB = BSZ / (256 * 16);
  const char* Ab = (const char*)Ap;
  const char* Bb = (const char*)Bt;

  f32x4 acc[2][BN / 16];
#pragma unroll
  for (int a = 0; a < 2; ++a)
#pragma unroll
    for (int b = 0; b < BN / 16; ++b) acc[a][b] = (f32x4)0.f;

  const int nk = K / BK;
  for (int t = 0; t < nk; ++t) {
    const int k0 = t * BK;
#pragma unroll
    for (int j = 0; j < NGA; ++j) {
      const int d = (j * 256 + tid) * 16;
      const int row = d / SBA;
      const int u = (d % SBA) ^ ((row & AMSK) << 4);
      int grow = row0 + row;
      if (grow >= M) grow = M - 1;  // clamp: harmless, stores guarded
      gl16(Ab + (size_t)grow * (size_t)(K * ABYT) + k0 * ABYT + u, as_ + d);
    }
#pragma unroll
    for (int j = 0; j < NGB; ++j) {
      const int d = (j * 256 + tid) * 16;
      const int n = d / SBB;
      const int u = (d % SBB) ^ ((n & BMSK) << 4);
      gl16(Bb + (size_t)n * (size_t)(K * 2) + k0 * 2 + u, bs_ + d);
    }
    __syncthreads();
#pragma unroll
    for (int kk = 0; kk < BK; kk += 32) {
      const int koff = kk + lg * 8;
      bf16x8 a0, a1;
      if constexpr (!ABF16) {
        const int b0 = (wid * 32 + l15) * SBA + koff * 4;
        const int b1 = b0 + 16 * SBA;
        const f32x4 q00 = *(const f32x4*)(as_ + (b0 ^ amsk));
        const f32x4 q01 = *(const f32x4*)(as_ + ((b0 ^ amsk) ^ 16));
        const f32x4 q10 = *(const f32x4*)(as_ + (b1 ^ amsk));
        const f32x4 q11 = *(const f32x4*)(as_ + ((b1 ^ amsk) ^ 16));
        a0 = pack8(q00, q01);
        a1 = pack8(q10, q11);
      } else {
        const int b0 = (wid * 32 + l15) * SBA + koff * 2;
        const int b1 = b0 + 16 * SBA;
        a0 = *(const bf16x8*)(as_ + (b0 ^ amsk));
        a1 = *(const bf16x8*)(as_ + (b1 ^ amsk));
      }
#pragma unroll
      for (int nf = 0; nf < BN / 16; ++nf) {
        const int n = nf * 16 + l15;
        const bf16x8 b = *(const bf16x8*)(bs_ + ((n * SBB + koff * 2) ^ bmsk));
        acc[0][nf] = __builtin_amdgcn_mfma_f32_16x16x32_bf16(a0, b, acc[0][nf], 0, 0, 0);
        acc[1][nf] = __builtin_amdgcn_mfma_f32_16x16x32_bf16(a1, b, acc[1][nf], 0, 0, 0);
      }
    }
    __syncthreads();
  }
  unsigned short* outl = (unsigned short*)lds;
#pragma unroll
  for (int pp = 0; pp < EP; ++pp) {
    if ((wid * 32) / ROWS_P == pp || EP == 1) {
#pragma unroll
      for (int mf = 0; mf < 2; ++mf)
#pragma unroll
        for (int nf = 0; nf < BN / 16; ++nf)
#pragma unroll
          for (int r = 0; r < 4; ++r) {
            const int row = wid * 32 + mf * 16 + lg * 4 + r;  // D: row=(lane>>4)*4+r
            const int col = nf * 16 + l15;                    //    col=lane&15
            outl[(row - pp * ROWS_P) * OUTP + col] = f2bf(acc[mf][nf][r]);
          }
    }
    __syncthreads();
#pragma unroll
    for (int i = tid; i < ROWS_P * (BN / 8); i += 256) {
      const int m = i / (BN / 8), c8 = i % (BN / 8);
      const int row = row0 + pp * ROWS_P + m;
      if (row < M)
        *(float4*)(&C[(size_t)row * BN + c8 * 8]) = *(const float4*)(&outl[m * OUTP + c8 * 8]);
    }
    if (EP > 1) __syncthreads();
  }
}

// ---------------- prep: W1^T, W3^T (bf16) ----------------
__global__ __launch_bounds__(256) void k_prep(const float* __restrict__ W1,
                                              const float* __restrict__ W3,
                                              unsigned short* __restrict__ w1t,
                                              unsigned short* __restrict__ w3t) {
  const int i = blockIdx.x * 256 + threadIdx.x;  // grid exact: PREP_NB
  if (i < DI * DH) {  // w1t[n][k] = W1[k][n]
    const int n = i / DI, k = i % DI;
    w1t[i] = f2bf(W1[k * DH + n]);
  } else {
    const int j = i - DI * DH;  // w3t[n][k] = W3[k][n]
    const int n = j / DH, k = j % DH;
    w3t[j] = f2bf(W3[k * DO + n]);
  }
}

// ---- fused: GEMM1 half-1 + CSR pass A (independent), 1:4 interleave ----
__global__ __launch_bounds__(256) void k_g1a(const float* __restrict__ x,
                                             const unsigned short* __restrict__ w1t,
                                             unsigned short* __restrict__ sup,
                                             const int* __restrict__ erow,
                                             int* __restrict__ gcnt,
                                             unsigned short* __restrict__ rank8) {
  const int b = blockIdx.x;  // grid: G1H * 5 = 1955
  if (b % 5 == 0) {
    gemm_block<128, 128, 64, false>(x, w1t, sup, NN, DI, b / 5);  // bx 0..390
  } else {
    const int k = (b / 5) * 4 + (b % 5) - 1;  // 0..1563
    if (k < NBA) {
      __shared__ int h[NBUK];
      const int tid = threadIdx.x;
      for (int i = tid; i < NBUK; i += 256) h[i] = 0;
      __syncthreads();
      const int e0 = k * EPB;
#pragma unroll
      for (int j = 0; j < 4; ++j) {
        const int e = e0 + j * 256 + tid;
        if (e < NE) rank8[e] = (unsigned short)atomicAdd(&h[erow[e] >> 8], 1);
      }
      __syncthreads();
      for (int i = tid; i < NBUK; i += 256) gcnt[(size_t)k * NBUK + i] = h[i];
    }
  }
}

// ---- CSR pass B1: per-bucket exclusive scan over blocks ----
__global__ __launch_bounds__(256) void k_passB1(const int* __restrict__ gcnt,
                                                int* __restrict__ boff,
                                                int* __restrict__ btot) {
  const int b = blockIdx.x, t = threadIdx.x;  // grid NBUK
  int v[7];
  int s = 0;
#pragma unroll
  for (int j = 0; j < 7; ++j) {
    const int k = t * 7 + j;
    v[j] = (k < NBA) ? gcnt[(size_t)k * NBUK + b] : 0;
    s += v[j];
  }
  __shared__ int ps[256];
  ps[t] = s;
  __syncthreads();
  for (int off = 1; off < 256; off <<= 1) {
    int x = (t >= off) ? ps[t - off] : 0;
    __syncthreads();
    ps[t] += x;
    __syncthreads();
  }
  int excl = ps[t] - s;
  if (t == 255) btot[b] = ps[255];
#pragma unroll
  for (int j = 0; j < 7; ++j) {
    const int k = t * 7 + j;
    if (k < NBA) boff[(size_t)b * NBA + k] = excl;
    excl += v[j];
  }
}

// ---- CSR pass B2: scan bucket totals -> bbase[0..NBUK]; + w2sum ----
__global__ __launch_bounds__(256) void k_passB2(const int* __restrict__ btot,
                                                int* __restrict__ bbase,
                                                int* __restrict__ rowptr,
                                                const float* __restrict__ W2,
                                                float* __restrict__ w2s) {
  if (blockIdx.x == 1) {
    const int kk = threadIdx.x;
    if (kk < DH) {
      float s = 0.f;
      for (int d = 0; d < DO; ++d) s += W2[kk * DO + d];
      w2s[kk] = s;
    }
    return;
  }
  __shared__ int sdat[512];
  const int t = threadIdx.x;
  sdat[t] = (t < NBUK) ? btot[t] : 0;
  sdat[t + 256] = (t + 256 < NBUK) ? btot[t + 256] : 0;
  __syncthreads();
  for (int off = 1; off < 512; off <<= 1) {
    const int x0 = (t >= off) ? sdat[t - off] : 0;
    const int x1 = (t + 256 >= off) ? sdat[t + 256 - off] : 0;
    __syncthreads();
    sdat[t] += x0;
    sdat[t + 256] += x1;
    __syncthreads();
  }
  if (t == 0) { bbase[0] = 0; rowptr[NN] = NE; }
  bbase[t + 1] = sdat[t];                       // bbase[1..256]
  if (t + 257 <= NBUK) bbase[t + 257] = sdat[t + 256];  // bbase[257..391]
}

// ---- fused: GEMM1 half-2 + CSR pass C (bucket placement), 1:4 interleave ----
__global__ __launch_bounds__(256) void k_g1b(const float* __restrict__ x,
                                             const unsigned short* __restrict__ w1t,
                                             unsigned short* __restrict__ sup,
                                             const int* __restrict__ erow,
                                             const int* __restrict__ ecol,
                                             const float* __restrict__ eval,
                                             const unsigned short* __restrict__ rank8,
                                             const int* __restrict__ boff,
                                             const int* __restrict__ bbase,
                                             uint2* __restrict__ scv) {
  const int b = blockIdx.x;  // grid: G1H * 5 = 1955
  if (b % 5 == 0) {
    gemm_block<128, 128, 64, false>(x, w1t, sup, NN, DI, G1H + b / 5);  // bx 391..781
  } else {
    const int k = (b / 5) * 4 + (b % 5) - 1;
    if (k < NBA) {
      const int e0 = k * EPB;
      const int tid = threadIdx.x;
#pragma unroll
      for (int j = 0; j < 4; ++j) {
        const int e = e0 + j * 256 + tid;
        if (e < NE) {
          const int r = erow[e];
          const int bu = r >> 8;
          const int pos = bbase[bu] + boff[(size_t)bu * NBA + k] + (int)rank8[e];
          scv[pos] = make_uint2(((unsigned)(r & 255) << 17) | (unsigned)ecol[e],
                                __float_as_uint(eval[e]));
        }
      }
    }
  }
}

// ---- CSR pass D: per-bucket counting sort (LDS only) -> cpk + rowptr ----
__global__ __launch_bounds__(256) void k_passD(const uint2* __restrict__ scv,
                                               const int* __restrict__ bbase,
                                               int* __restrict__ rowptr,
                                               int2* __restrict__ cpk) {
  const int b = blockIdx.x, t = threadIdx.x;  // grid NBUK
  const int lo = bbase[b], hi = bbase[b + 1];
  __shared__ int c1[256], sc[256];
  c1[t] = 0;
  __syncthreads();
  for (int e = lo + t; e < hi; e += 256) atomicAdd(&c1[scv[e].x >> 17], 1);
  __syncthreads();
  const int my = c1[t];
  sc[t] = my;
  __syncthreads();
  for (int off = 1; off < 256; off <<= 1) {
    const int xx = (t >= off) ? sc[t - off] : 0;
    __syncthreads();
    sc[t] += xx;
    __syncthreads();
  }
  const int ro = sc[t] - my;  // exclusive in-bucket row offset
  const int gr = b * 256 + t;
  if (gr < NN) rowptr[gr] = lo + ro;
  c1[t] = 0;   // reuse as placement counters
  sc[t] = ro;  // keep offsets for all rows
  __syncthreads();
  for (int e = lo + t; e < hi; e += 256) {
    const uint2 q = scv[e];
    const int i = (int)(q.x >> 17);
    const int p = lo + sc[i] + atomicAdd(&c1[i], 1);
    cpk[p] = make_int2((int)(q.x & 0x1FFFFu), (int)q.y);
  }
}

// ---------------- SPMM1: 16 lanes/row, 4-deep unroll ----------------------
__global__ __launch_bounds__(256) void k_spmm1(const unsigned short* __restrict__ sup1,
                                               const int* __restrict__ rowptr,
                                               const int2* __restrict__ cpk,
                                               const float* __restrict__ w2s,
                                               unsigned short* __restrict__ h1,
                                               float* __restrict__ hw) {
  const int tid = threadIdx.x;
  const int lane = tid & 15;                       // 16 lanes x 8 bf16 = 128 ch
  const int r = blockIdx.x * 16 + (tid >> 4);      // grid exact: NN/16
  const int e0 = rowptr[r];
  const int e1 = rowptr[r + 1];
  const uint4* s8 = reinterpret_cast<const uint4*>(sup1);  // 16B = 8 bf16
  float aA[8] = {0,0,0,0,0,0,0,0}, aB[8] = {0,0,0,0,0,0,0,0};
  float aC[8] = {0,0,0,0,0,0,0,0}, aD[8] = {0,0,0,0,0,0,0,0};
  int e = e0;
  for (; e + 4 <= e1; e += 4) {
    const int2 p0 = cpk[e],     p1 = cpk[e + 1];
    const int2 p2 = cpk[e + 2], p3 = cpk[e + 3];
    const uint4 g0 = s8[(size_t)p0.x * 16 + lane];
    const uint4 g1 = s8[(size_t)p1.x * 16 + lane];
    const uint4 g2 = s8[(size_t)p2.x * 16 + lane];
    const uint4 g3 = s8[(size_t)p3.x * 16 + lane];
    fma8(aA, g0, __int_as_float(p0.y));
    fma8(aB, g1, __int_as_float(p1.y));
    fma8(aC, g2, __int_as_float(p2.y));
    fma8(aD, g3, __int_as_float(p3.y));
  }
  if (e + 2 <= e1) {
    const int2 p0 = cpk[e], p1 = cpk[e + 1];
    const uint4 g0 = s8[(size_t)p0.x * 16 + lane];
    const uint4 g1 = s8[(size_t)p1.x * 16 + lane];
    fma8(aA, g0, __int_as_float(p0.y));
    fma8(aB, g1, __int_as_float(p1.y));
    e += 2;
  }
  if (e < e1) {
    const int2 p0 = cpk[e];
    const uint4 g0 = s8[(size_t)p0.x * 16 + lane];
    fma8(aC, g0, __int_as_float(p0.y));
  }
  float acc[8];
#pragma unroll
  for (int j = 0; j < 8; ++j) acc[j] = fmaxf((aA[j] + aB[j]) + (aC[j] + aD[j]), 0.f);
  uint4 o;
  o.x = (unsigned)f2bf(acc[0]) | ((unsigned)f2bf(acc[1]) << 16);
  o.y = (unsigned)f2bf(acc[2]) | ((unsigned)f2bf(acc[3]) << 16);
  o.z = (unsigned)f2bf(acc[4]) | ((unsigned)f2bf(acc[5]) << 16);
  o.w = (unsigned)f2bf(acc[6]) | ((unsigned)f2bf(acc[7]) << 16);
  reinterpret_cast<uint4*>(h1)[(size_t)r * 16 + lane] = o;
  // hw[r] = relu_row . w2sum  (feeds the folded z_mu)
  const float4 wlo = reinterpret_cast<const float4*>(w2s)[lane * 2];
  const float4 whi = reinterpret_cast<const float4*>(w2s)[lane * 2 + 1];
  float p = acc[0] * wlo.x + acc[1] * wlo.y + acc[2] * wlo.z + acc[3] * wlo.w +
            acc[4] * whi.x + acc[5] * whi.y + acc[6] * whi.z + acc[7] * whi.w;
#pragma unroll
  for (int off = 8; off > 0; off >>= 1) p += __shfl_down(p, off, 16);
  if (lane == 0) hw[r] = p;
}

// ---------------- fused: GEMM2 (LDS-staged) + edot ------------------------
__global__ __launch_bounds__(256) void k_g2_edot(const unsigned short* __restrict__ h1,
                                                 const unsigned short* __restrict__ w3t,
                                                 unsigned short* __restrict__ sup,
                                                 const int* __restrict__ ecol,
                                                 const float* __restrict__ eval,
                                                 const float* __restrict__ hw,
                                                 float* __restrict__ pzmu) {
  const int b = blockIdx.x;  // grid: G1_NB * 9 = 7038
  if (b % 9 == 0) {
    gemm_block<128, 64, 64, true>(h1, w3t, sup, NN, DH, b / 9);
  } else {
    const int eb = (b / 9) * 8 + (b % 9) - 1;
    if (eb < EDOT_NB) {
      __shared__ float red[256];
      const int i = eb * 256 + threadIdx.x;
      red[threadIdx.x] = eval[i] * hw[ecol[i]];
      __syncthreads();
      for (int off = 128; off > 0; off >>= 1) {
        if (threadIdx.x < off) red[threadIdx.x] += red[threadIdx.x + off];
        __syncthreads();
      }
      if (threadIdx.x == 0) pzmu[eb] = red[0];
    }
  }
}

// ---------------- SPMM3 + exp + reduce (8 lanes/row, 4-deep unroll) -------
__global__ __launch_bounds__(256) void k_spmm3(const unsigned short* __restrict__ sup3,
                                               const int* __restrict__ rowptr,
                                               const int2* __restrict__ cpk,
                                               float* __restrict__ pexp) {
  const int tid = threadIdx.x;
  const int lane = tid & 7;
  const int r = blockIdx.x * 32 + (tid >> 3);  // grid exact: NN/32
  const int e0 = rowptr[r];
  const int e1 = rowptr[r + 1];
  const uint4* s8 = reinterpret_cast<const uint4*>(sup3);
  float aA[8] = {0,0,0,0,0,0,0,0}, aB[8] = {0,0,0,0,0,0,0,0};
  float aC[8] = {0,0,0,0,0,0,0,0}, aD[8] = {0,0,0,0,0,0,0,0};
  int e = e0;
  for (; e + 4 <= e1; e += 4) {
    const int2 p0 = cpk[e],     p1 = cpk[e + 1];
    const int2 p2 = cpk[e + 2], p3 = cpk[e + 3];
    const uint4 g0 = s8[(size_t)p0.x * 8 + lane];
    const uint4 g1 = s8[(size_t)p1.x * 8 + lane];
    const uint4 g2 = s8[(size_t)p2.x * 8 + lane];
    const uint4 g3 = s8[(size_t)p3.x * 8 + lane];
    fma8(aA, g0, __int_as_float(p0.y));
    fma8(aB, g1, __int_as_float(p1.y));
    fma8(aC, g2, __int_as_float(p2.y));
    fma8(aD, g3, __int_as_float(p3.y));
  }
  if (e + 2 <= e1) {
    const int2 p0 = cpk[e], p1 = cpk[e + 1];
    const uint4 g0 = s8[(size_t)p0.x * 8 + lane];
    const uint4 g1 = s8[(size_t)p1.x * 8 + lane];
    fma8(aA, g0, __int_as_float(p0.y));
    fma8(aB, g1, __int_as_float(p1.y));
    e += 2;
  }
  if (e < e1) {
    const int2 p0 = cpk[e];
    const uint4 g0 = s8[(size_t)p0.x * 8 + lane];
    fma8(aC, g0, __int_as_float(p0.y));
  }
  float p = 0.f;
#pragma unroll
  for (int j = 0; j < 8; ++j) p += expf((aA[j] + aB[j]) + (aC[j] + aD[j]));
#pragma unroll
  for (int off = 4; off > 0; off >>= 1) p += __shfl_down(p, off, 8);
  __shared__ float part[32];
  if (lane == 0) part[tid >> 3] = p;
  __syncthreads();
  if (tid == 0) {
    float s = 0.f;
#pragma unroll
    for (int i = 0; i < 32; ++i) s += part[i];
    pexp[blockIdx.x] = s;
  }
}

// ---------------- finalize ----------------
__global__ __launch_bounds__(256) void k_final(const float* __restrict__ pzmu, int nz,
                                               const float* __restrict__ pexp, int ne,
                                               float* __restrict__ out) {
  __shared__ float red[256];
  const int t = threadIdx.x;
  float s1 = 0.f, s2 = 0.f;
  for (int i = t; i < nz; i += 256) s1 += pzmu[i];
  for (int i = t; i < ne; i += 256) s2 += pexp[i];
  red[t] = s1;
  __syncthreads();
  for (int off = 128; off > 0; off >>= 1) {
    if (t < off) red[t] += red[t + off];
    __syncthreads();
  }
  const float tot1 = red[0];
  __syncthreads();
  red[t] = s2;
  __syncthreads();
  for (int off = 128; off > 0; off >>= 1) {
    if (t < off) red[t] += red[t + off];
    __syncthreads();
  }
  if (t == 0) {
    const float denom = (float)NN * (float)DO;  // mean over [N, 64]
    out[0] = tot1 / denom;
    out[1] = logf(red[0] / denom);
  }
}

}  // namespace

extern "C" void kernel_launch(void* const* d_in, const int* in_sizes, int n_in,
                              void* d_out, int out_size, void* d_ws, size_t ws_size,
                              hipStream_t stream) {
  const float* x    = (const float*)d_in[0];
  const int*   erow = (const int*)d_in[1];
  const int*   ecol = (const int*)d_in[2];
  const float* eval = (const float*)d_in[3];
  const float* W1   = (const float*)d_in[4];
  const float* W2   = (const float*)d_in[5];
  const float* W3   = (const float*)d_in[6];
  float* out = (float*)d_out;

  // workspace carve-out (256B aligned); peak ~85 MB
  char* p = (char*)d_ws;
  auto alloc = [&](size_t bytes) -> void* {
    void* r = (void*)p;
    p += (bytes + 255) & ~(size_t)255;
    return r;
  };
  unsigned short* sup = (unsigned short*)alloc((size_t)NN * DH * 2);  // support1; reused as support3
  unsigned short* h1  = (unsigned short*)alloc((size_t)NN * DH * 2);  // h1 bf16
  int2*  cpk    = (int2*)alloc((size_t)NE * 8);   // final CSR (col, valbits)
  uint2* scv    = (uint2*)alloc((size_t)NE * 8);  // bucket-sorted (low8|col, valbits)
  unsigned short* rank8 = (unsigned short*)alloc((size_t)NE * 2);
  int*   rowptr = (int*)alloc((size_t)(NN + 1) * 4);
  int*   gcnt   = (int*)alloc((size_t)NBA * NBUK * 4);  // [block][bucket]
  int*   boff   = (int*)alloc((size_t)NBUK * NBA * 4);  // [bucket][block]
  int*   btot   = (int*)alloc((size_t)NBUK * 4);
  int*   bbase  = (int*)alloc((size_t)(NBUK + 1) * 4);
  float* hw     = (float*)alloc((size_t)NN * 4);
  float* w2s    = (float*)alloc(DH * 4);
  unsigned short* w1t = (unsigned short*)alloc((size_t)DH * DI * 2);  // W1^T bf16 [128][256]
  unsigned short* w3t = (unsigned short*)alloc((size_t)DO * DH * 2);  // W3^T bf16 [64][128]
  float* pexp   = (float*)alloc(SP3_NB * 4);
  float* pzmu   = (float*)alloc(EDOT_NB * 4);

  // weight prep first (GEMM1 consumes w1t)
  k_prep<<<PREP_NB, 256, 0, stream>>>(W1, W3, w1t, w3t);

  // GEMM1 half-1 interleaved with CSR pass A (both independent)
  k_g1a<<<G1H * 5, 256, 0, stream>>>(x, w1t, sup, erow, gcnt, rank8);
  // small serial scans
  k_passB1<<<NBUK, 256, 0, stream>>>(gcnt, boff, btot);
  k_passB2<<<2, 256, 0, stream>>>(btot, bbase, rowptr, W2, w2s);
  // GEMM1 half-2 interleaved with bucket placement
  k_g1b<<<G1H * 5, 256, 0, stream>>>(x, w1t, sup, erow, ecol, eval,
                                     rank8, boff, bbase, scv);
  // per-bucket counting sort -> cpk + rowptr
  k_passD<<<NBUK, 256, 0, stream>>>(scv, bbase, rowptr, cpk);

  // h1 = relu(spmm(support1)) [bf16]; hw = h1 . w2sum   (mu branch folded)
  k_spmm1<<<NN / 16, 256, 0, stream>>>(sup, rowptr, cpk, w2s, h1, hw);

  // fused: GEMM2 (support3 = h1@W3, MFMA) + z_mu edge-dot partials
  k_g2_edot<<<G1_NB * 9, 256, 0, stream>>>(h1, w3t, sup, ecol, eval, hw, pzmu);

  // logvar spmm fused with sum(exp(.)) -> per-block partials
  k_spmm3<<<NN / 32, 256, 0, stream>>>(sup, rowptr, cpk, pexp);

  k_final<<<1, 256, 0, stream>>>(pzmu, EDOT_NB, pexp, SP3_NB, out);
}

// Round 20
// 197.942 us; speedup vs baseline: 1.0473x; 1.0473x over previous
//
#include <hip/hip_runtime.h>
#include <cstdint>
#include <cstddef>

namespace {

constexpr int NN = 100000;   // nodes
constexpr int NE = 1600000;  // edges
constexpr int DI = 256;
constexpr int DH = 128;
constexpr int DO = 64;
constexpr int EPB = 1024;                     // edges per bucket-hist block
constexpr int NBA = (NE + EPB - 1) / EPB;     // 1563
constexpr int NBUK = (NN + 255) / 256;        // 391 buckets of 256 rows
constexpr int EDOT_NB = NE / 256;   // 6250
constexpr int SP3_NB = NN / 32;     // 3125
constexpr int G1_NB = (NN + 127) / 128;  // 782 gemm blocks
constexpr int PREP_NB = (DI * DH + DH * DO) / 256;  // 160

using bf16x8 = __attribute__((ext_vector_type(8))) short;  // 8 bf16 = 4 VGPR
using f32x4  = __attribute__((ext_vector_type(4))) float;

__device__ inline unsigned short f2bf(float f) {
  unsigned int u = __float_as_uint(f);
  u += 0x7FFFu + ((u >> 16) & 1u);  // round-to-nearest-even
  return (unsigned short)(u >> 16);
}
__device__ inline float bflo(unsigned int u) { return __uint_as_float(u << 16); }
__device__ inline float bfhi(unsigned int u) { return __uint_as_float(u & 0xffff0000u); }

__device__ inline void fma8(float* acc, const uint4 g, const float v) {
  acc[0] = fmaf(v, bflo(g.x), acc[0]); acc[1] = fmaf(v, bfhi(g.x), acc[1]);
  acc[2] = fmaf(v, bflo(g.y), acc[2]); acc[3] = fmaf(v, bfhi(g.y), acc[3]);
  acc[4] = fmaf(v, bflo(g.z), acc[4]); acc[5] = fmaf(v, bfhi(g.z), acc[5]);
  acc[6] = fmaf(v, bflo(g.w), acc[6]); acc[7] = fmaf(v, bfhi(g.w), acc[7]);
}

// async global->LDS, 16B per lane; LDS dest = wave-uniform base + lane*16
__device__ __forceinline__ void gl16(const void* g, void* l) {
  __builtin_amdgcn_global_load_lds(
      (const __attribute__((address_space(1))) void*)g,
      (__attribute__((address_space(3))) void*)l, 16, 0, 0);
}

__device__ __forceinline__ bf16x8 pack8(const f32x4 lo, const f32x4 hi) {
  bf16x8 r;
  r[0] = (short)f2bf(lo[0]); r[1] = (short)f2bf(lo[1]);
  r[2] = (short)f2bf(lo[2]); r[3] = (short)f2bf(lo[3]);
  r[4] = (short)f2bf(hi[0]); r[5] = (short)f2bf(hi[1]);
  r[6] = (short)f2bf(hi[2]); r[7] = (short)f2bf(hi[3]);
  return r;
}

// ---- MFMA GEMM block body: gload_lds staging, swizzle masks clamped
// per-operand, EP-pass epilogue. (round-13 verified structure) ----
template <int BM, int BN, int BK, bool ABF16>
__device__ __forceinline__ void gemm_block(const void* __restrict__ Ap,
                                           const unsigned short* __restrict__ Bt,
                                           unsigned short* __restrict__ C,
                                           int M, int K, int bx) {
  constexpr int ABYT = ABF16 ? 2 : 4;
  constexpr int SBA = BK * ABYT;
  constexpr int SBB = BK * 2;
  constexpr int ASZ = BM * SBA;
  constexpr int BSZ = BN * SBB;
  constexpr int STAGE = ASZ + BSZ;
  constexpr int OUTP = BN + 8;
  constexpr int EP = (BM * OUTP * 2 > STAGE) ? 2 : 1;
  constexpr int ROWS_P = BM / EP;
  constexpr int OUTB = ROWS_P * OUTP * 2;
  constexpr int LDSB = STAGE > OUTB ? STAGE : OUTB;
  constexpr int AMSK = (SBA / 16 - 1) > 7 ? 7 : (SBA / 16 - 1);
  constexpr int BMSK = (SBB / 16 - 1) > 7 ? 7 : (SBB / 16 - 1);
  __shared__ __align__(16) char lds[LDSB];
  char* const as_ = lds;
  char* const bs_ = lds + ASZ;

  const int tid = threadIdx.x;
  const int wid = tid >> 6;
  const int lane = tid & 63;
  const int l15 = lane & 15;
  const int lg = lane >> 4;
  const int amsk = (l15 & AMSK) << 4;
  const int bmsk = (l15 & BMSK) << 4;
  const int row0 = bx * BM;

  constexpr int NGA = ASZ / (256 * 16);
  constexpr int NGB = BSZ / (256 * 16);
  const char* Ab = (const char*)Ap;
  const char* Bb = (const char*)Bt;

  f32x4 acc[2][BN / 16];
#pragma unroll
  for (int a = 0; a < 2; ++a)
#pragma unroll
    for (int b = 0; b < BN / 16; ++b) acc[a][b] = (f32x4)0.f;

  const int nk = K / BK;
  for (int t = 0; t < nk; ++t) {
    const int k0 = t * BK;
#pragma unroll
    for (int j = 0; j < NGA; ++j) {
      const int d = (j * 256 + tid) * 16;
      const int row = d / SBA;
      const int u = (d % SBA) ^ ((row & AMSK) << 4);
      int grow = row0 + row;
      if (grow >= M) grow = M - 1;  // clamp: harmless, stores guarded
      gl16(Ab + (size_t)grow * (size_t)(K * ABYT) + k0 * ABYT + u, as_ + d);
    }
#pragma unroll
    for (int j = 0; j < NGB; ++j) {
      const int d = (j * 256 + tid) * 16;
      const int n = d / SBB;
      const int u = (d % SBB) ^ ((n & BMSK) << 4);
      gl16(Bb + (size_t)n * (size_t)(K * 2) + k0 * 2 + u, bs_ + d);
    }
    __syncthreads();
#pragma unroll
    for (int kk = 0; kk < BK; kk += 32) {
      const int koff = kk + lg * 8;
      bf16x8 a0, a1;
      if constexpr (!ABF16) {
        const int b0 = (wid * 32 + l15) * SBA + koff * 4;
        const int b1 = b0 + 16 * SBA;
        const f32x4 q00 = *(const f32x4*)(as_ + (b0 ^ amsk));
        const f32x4 q01 = *(const f32x4*)(as_ + ((b0 ^ amsk) ^ 16));
        const f32x4 q10 = *(const f32x4*)(as_ + (b1 ^ amsk));
        const f32x4 q11 = *(const f32x4*)(as_ + ((b1 ^ amsk) ^ 16));
        a0 = pack8(q00, q01);
        a1 = pack8(q10, q11);
      } else {
        const int b0 = (wid * 32 + l15) * SBA + koff * 2;
        const int b1 = b0 + 16 * SBA;
        a0 = *(const bf16x8*)(as_ + (b0 ^ amsk));
        a1 = *(const bf16x8*)(as_ + (b1 ^ amsk));
      }
#pragma unroll
      for (int nf = 0; nf < BN / 16; ++nf) {
        const int n = nf * 16 + l15;
        const bf16x8 b = *(const bf16x8*)(bs_ + ((n * SBB + koff * 2) ^ bmsk));
        acc[0][nf] = __builtin_amdgcn_mfma_f32_16x16x32_bf16(a0, b, acc[0][nf], 0, 0, 0);
        acc[1][nf] = __builtin_amdgcn_mfma_f32_16x16x32_bf16(a1, b, acc[1][nf], 0, 0, 0);
      }
    }
    __syncthreads();
  }
  unsigned short* outl = (unsigned short*)lds;
#pragma unroll
  for (int pp = 0; pp < EP; ++pp) {
    if ((wid * 32) / ROWS_P == pp || EP == 1) {
#pragma unroll
      for (int mf = 0; mf < 2; ++mf)
#pragma unroll
        for (int nf = 0; nf < BN / 16; ++nf)
#pragma unroll
          for (int r = 0; r < 4; ++r) {
            const int row = wid * 32 + mf * 16 + lg * 4 + r;  // D: row=(lane>>4)*4+r
            const int col = nf * 16 + l15;                    //    col=lane&15
            outl[(row - pp * ROWS_P) * OUTP + col] = f2bf(acc[mf][nf][r]);
          }
    }
    __syncthreads();
#pragma unroll
    for (int i = tid; i < ROWS_P * (BN / 8); i += 256) {
      const int m = i / (BN / 8), c8 = i % (BN / 8);
      const int row = row0 + pp * ROWS_P + m;
      if (row < M)
        *(float4*)(&C[(size_t)row * BN + c8 * 8]) = *(const float4*)(&outl[m * OUTP + c8 * 8]);
    }
    if (EP > 1) __syncthreads();
  }
}

// ---------------- prep: W1^T, W3^T (bf16) ----------------
__global__ __launch_bounds__(256) void k_prep(const float* __restrict__ W1,
                                              const float* __restrict__ W3,
                                              unsigned short* __restrict__ w1t,
                                              unsigned short* __restrict__ w3t) {
  const int i = blockIdx.x * 256 + threadIdx.x;  // grid exact: PREP_NB
  if (i < DI * DH) {  // w1t[n][k] = W1[k][n]
    const int n = i / DI, k = i % DI;
    w1t[i] = f2bf(W1[k * DH + n]);
  } else {
    const int j = i - DI * DH;  // w3t[n][k] = W3[k][n]
    const int n = j / DH, k = j % DH;
    w3t[j] = f2bf(W3[k * DO + n]);
  }
}

// ---- CSR pass A: per-block LDS histogram over 391 coarse buckets ----
__global__ __launch_bounds__(256) void k_passA(const int* __restrict__ erow,
                                               int* __restrict__ gcnt,
                                               unsigned short* __restrict__ rank8) {
  __shared__ int h[NBUK];
  const int tid = threadIdx.x, k = blockIdx.x;  // grid NBA
  for (int i = tid; i < NBUK; i += 256) h[i] = 0;
  __syncthreads();
  const int e0 = k * EPB;
#pragma unroll
  for (int j = 0; j < 4; ++j) {
    const int e = e0 + j * 256 + tid;
    if (e < NE) rank8[e] = (unsigned short)atomicAdd(&h[erow[e] >> 8], 1);
  }
  __syncthreads();
  for (int i = tid; i < NBUK; i += 256) gcnt[(size_t)k * NBUK + i] = h[i];
}

// ---- CSR pass B1: per-bucket exclusive scan over blocks ----
__global__ __launch_bounds__(256) void k_passB1(const int* __restrict__ gcnt,
                                                int* __restrict__ boff,
                                                int* __restrict__ btot) {
  const int b = blockIdx.x, t = threadIdx.x;  // grid NBUK
  int v[7];
  int s = 0;
#pragma unroll
  for (int j = 0; j < 7; ++j) {
    const int k = t * 7 + j;
    v[j] = (k < NBA) ? gcnt[(size_t)k * NBUK + b] : 0;
    s += v[j];
  }
  __shared__ int ps[256];
  ps[t] = s;
  __syncthreads();
  for (int off = 1; off < 256; off <<= 1) {
    int x = (t >= off) ? ps[t - off] : 0;
    __syncthreads();
    ps[t] += x;
    __syncthreads();
  }
  int excl = ps[t] - s;
  if (t == 255) btot[b] = ps[255];
#pragma unroll
  for (int j = 0; j < 7; ++j) {
    const int k = t * 7 + j;
    if (k < NBA) boff[(size_t)b * NBA + k] = excl;
    excl += v[j];
  }
}

// ---- CSR pass B2: scan bucket totals -> bbase[0..NBUK]; + w2sum ----
__global__ __launch_bounds__(256) void k_passB2(const int* __restrict__ btot,
                                                int* __restrict__ bbase,
                                                int* __restrict__ rowptr,
                                                const float* __restrict__ W2,
                                                float* __restrict__ w2s) {
  if (blockIdx.x == 1) {
    const int kk = threadIdx.x;
    if (kk < DH) {
      float s = 0.f;
      for (int d = 0; d < DO; ++d) s += W2[kk * DO + d];
      w2s[kk] = s;
    }
    return;
  }
  __shared__ int sdat[512];
  const int t = threadIdx.x;
  sdat[t] = (t < NBUK) ? btot[t] : 0;
  sdat[t + 256] = (t + 256 < NBUK) ? btot[t + 256] : 0;
  __syncthreads();
  for (int off = 1; off < 512; off <<= 1) {
    const int x0 = (t >= off) ? sdat[t - off] : 0;
    const int x1 = (t + 256 >= off) ? sdat[t + 256 - off] : 0;
    __syncthreads();
    sdat[t] += x0;
    sdat[t + 256] += x1;
    __syncthreads();
  }
  if (t == 0) { bbase[0] = 0; rowptr[NN] = NE; }
  bbase[t + 1] = sdat[t];                       // bbase[1..256]
  if (t + 257 <= NBUK) bbase[t + 257] = sdat[t + 256];  // bbase[257..391]
}

// ---- fused: GEMM1 (BK=64, LDS-staged) + CSR pass C (bucket placement) ----
__global__ __launch_bounds__(256) void k_cg1(const float* __restrict__ x,
                                             const unsigned short* __restrict__ w1t,
                                             unsigned short* __restrict__ sup,
                                             const int* __restrict__ erow,
                                             const int* __restrict__ ecol,
                                             const float* __restrict__ eval,
                                             const unsigned short* __restrict__ rank8,
                                             const int* __restrict__ boff,
                                             const int* __restrict__ bbase,
                                             uint2* __restrict__ scv) {
  const int b = blockIdx.x;  // grid: G1_NB + NBA
  if (b < G1_NB) {
    gemm_block<128, 128, 64, false>(x, w1t, sup, NN, DI, b);
  } else {
    const int k = b - G1_NB;
    const int e0 = k * EPB;
    const int tid = threadIdx.x;
#pragma unroll
    for (int j = 0; j < 4; ++j) {
      const int e = e0 + j * 256 + tid;
      if (e < NE) {
        const int r = erow[e];
        const int bu = r >> 8;
        const int pos = bbase[bu] + boff[(size_t)bu * NBA + k] + (int)rank8[e];
        scv[pos] = make_uint2(((unsigned)(r & 255) << 17) | (unsigned)ecol[e],
                              __float_as_uint(eval[e]));
      }
    }
  }
}

// ---- CSR pass D: per-bucket counting sort (LDS only) -> cpk + rowptr ----
__global__ __launch_bounds__(256) void k_passD(const uint2* __restrict__ scv,
                                               const int* __restrict__ bbase,
                                               int* __restrict__ rowptr,
                                               int2* __restrict__ cpk) {
  const int b = blockIdx.x, t = threadIdx.x;  // grid NBUK
  const int lo = bbase[b], hi = bbase[b + 1];
  __shared__ int c1[256], sc[256];
  c1[t] = 0;
  __syncthreads();
  for (int e = lo + t; e < hi; e += 256) atomicAdd(&c1[scv[e].x >> 17], 1);
  __syncthreads();
  const int my = c1[t];
  sc[t] = my;
  __syncthreads();
  for (int off = 1; off < 256; off <<= 1) {
    const int xx = (t >= off) ? sc[t - off] : 0;
    __syncthreads();
    sc[t] += xx;
    __syncthreads();
  }
  const int ro = sc[t] - my;  // exclusive in-bucket row offset
  const int gr = b * 256 + t;
  if (gr < NN) rowptr[gr] = lo + ro;
  c1[t] = 0;   // reuse as placement counters
  sc[t] = ro;  // keep offsets for all rows
  __syncthreads();
  for (int e = lo + t; e < hi; e += 256) {
    const uint2 q = scv[e];
    const int i = (int)(q.x >> 17);
    const int p = lo + sc[i] + atomicAdd(&c1[i], 1);
    cpk[p] = make_int2((int)(q.x & 0x1FFFFu), (int)q.y);
  }
}

// ---------------- SPMM1: 16 lanes/row, 4-deep unroll ----------------------
__global__ __launch_bounds__(256) void k_spmm1(const unsigned short* __restrict__ sup1,
                                               const int* __restrict__ rowptr,
                                               const int2* __restrict__ cpk,
                                               const float* __restrict__ w2s,
                                               unsigned short* __restrict__ h1,
                                               float* __restrict__ hw) {
  const int tid = threadIdx.x;
  const int lane = tid & 15;                       // 16 lanes x 8 bf16 = 128 ch
  const int r = blockIdx.x * 16 + (tid >> 4);      // grid exact: NN/16
  const int e0 = rowptr[r];
  const int e1 = rowptr[r + 1];
  const uint4* s8 = reinterpret_cast<const uint4*>(sup1);  // 16B = 8 bf16
  float aA[8] = {0,0,0,0,0,0,0,0}, aB[8] = {0,0,0,0,0,0,0,0};
  float aC[8] = {0,0,0,0,0,0,0,0}, aD[8] = {0,0,0,0,0,0,0,0};
  int e = e0;
  for (; e + 4 <= e1; e += 4) {
    const int2 p0 = cpk[e],     p1 = cpk[e + 1];
    const int2 p2 = cpk[e + 2], p3 = cpk[e + 3];
    const uint4 g0 = s8[(size_t)p0.x * 16 + lane];
    const uint4 g1 = s8[(size_t)p1.x * 16 + lane];
    const uint4 g2 = s8[(size_t)p2.x * 16 + lane];
    const uint4 g3 = s8[(size_t)p3.x * 16 + lane];
    fma8(aA, g0, __int_as_float(p0.y));
    fma8(aB, g1, __int_as_float(p1.y));
    fma8(aC, g2, __int_as_float(p2.y));
    fma8(aD, g3, __int_as_float(p3.y));
  }
  if (e + 2 <= e1) {
    const int2 p0 = cpk[e], p1 = cpk[e + 1];
    const uint4 g0 = s8[(size_t)p0.x * 16 + lane];
    const uint4 g1 = s8[(size_t)p1.x * 16 + lane];
    fma8(aA, g0, __int_as_float(p0.y));
    fma8(aB, g1, __int_as_float(p1.y));
    e += 2;
  }
  if (e < e1) {
    const int2 p0 = cpk[e];
    const uint4 g0 = s8[(size_t)p0.x * 16 + lane];
    fma8(aC, g0, __int_as_float(p0.y));
  }
  float acc[8];
#pragma unroll
  for (int j = 0; j < 8; ++j) acc[j] = fmaxf((aA[j] + aB[j]) + (aC[j] + aD[j]), 0.f);
  uint4 o;
  o.x = (unsigned)f2bf(acc[0]) | ((unsigned)f2bf(acc[1]) << 16);
  o.y = (unsigned)f2bf(acc[2]) | ((unsigned)f2bf(acc[3]) << 16);
  o.z = (unsigned)f2bf(acc[4]) | ((unsigned)f2bf(acc[5]) << 16);
  o.w = (unsigned)f2bf(acc[6]) | ((unsigned)f2bf(acc[7]) << 16);
  reinterpret_cast<uint4*>(h1)[(size_t)r * 16 + lane] = o;
  // hw[r] = relu_row . w2sum  (feeds the folded z_mu)
  const float4 wlo = reinterpret_cast<const float4*>(w2s)[lane * 2];
  const float4 whi = reinterpret_cast<const float4*>(w2s)[lane * 2 + 1];
  float p = acc[0] * wlo.x + acc[1] * wlo.y + acc[2] * wlo.z + acc[3] * wlo.w +
            acc[4] * whi.x + acc[5] * whi.y + acc[6] * whi.z + acc[7] * whi.w;
#pragma unroll
  for (int off = 8; off > 0; off >>= 1) p += __shfl_down(p, off, 16);
  if (lane == 0) hw[r] = p;
}

// ---------------- fused: GEMM2 (LDS-staged) + edot ------------------------
__global__ __launch_bounds__(256) void k_g2_edot(const unsigned short* __restrict__ h1,
                                                 const unsigned short* __restrict__ w3t,
                                                 unsigned short* __restrict__ sup,
                                                 const int* __restrict__ ecol,
                                                 const float* __restrict__ eval,
                                                 const float* __restrict__ hw,
                                                 float* __restrict__ pzmu) {
  const int b = blockIdx.x;  // grid: G1_NB * 9 = 7038
  if (b % 9 == 0) {
    gemm_block<128, 64, 64, true>(h1, w3t, sup, NN, DH, b / 9);
  } else {
    const int eb = (b / 9) * 8 + (b % 9) - 1;
    if (eb < EDOT_NB) {
      __shared__ float red[256];
      const int i = eb * 256 + threadIdx.x;
      red[threadIdx.x] = eval[i] * hw[ecol[i]];
      __syncthreads();
      for (int off = 128; off > 0; off >>= 1) {
        if (threadIdx.x < off) red[threadIdx.x] += red[threadIdx.x + off];
        __syncthreads();
      }
      if (threadIdx.x == 0) pzmu[eb] = red[0];
    }
  }
}

// ---------------- SPMM3 + exp + reduce (8 lanes/row, 4-deep unroll) -------
__global__ __launch_bounds__(256) void k_spmm3(const unsigned short* __restrict__ sup3,
                                               const int* __restrict__ rowptr,
                                               const int2* __restrict__ cpk,
                                               float* __restrict__ pexp) {
  const int tid = threadIdx.x;
  const int lane = tid & 7;
  const int r = blockIdx.x * 32 + (tid >> 3);  // grid exact: NN/32
  const int e0 = rowptr[r];
  const int e1 = rowptr[r + 1];
  const uint4* s8 = reinterpret_cast<const uint4*>(sup3);
  float aA[8] = {0,0,0,0,0,0,0,0}, aB[8] = {0,0,0,0,0,0,0,0};
  float aC[8] = {0,0,0,0,0,0,0,0}, aD[8] = {0,0,0,0,0,0,0,0};
  int e = e0;
  for (; e + 4 <= e1; e += 4) {
    const int2 p0 = cpk[e],     p1 = cpk[e + 1];
    const int2 p2 = cpk[e + 2], p3 = cpk[e + 3];
    const uint4 g0 = s8[(size_t)p0.x * 8 + lane];
    const uint4 g1 = s8[(size_t)p1.x * 8 + lane];
    const uint4 g2 = s8[(size_t)p2.x * 8 + lane];
    const uint4 g3 = s8[(size_t)p3.x * 8 + lane];
    fma8(aA, g0, __int_as_float(p0.y));
    fma8(aB, g1, __int_as_float(p1.y));
    fma8(aC, g2, __int_as_float(p2.y));
    fma8(aD, g3, __int_as_float(p3.y));
  }
  if (e + 2 <= e1) {
    const int2 p0 = cpk[e], p1 = cpk[e + 1];
    const uint4 g0 = s8[(size_t)p0.x * 8 + lane];
    const uint4 g1 = s8[(size_t)p1.x * 8 + lane];
    fma8(aA, g0, __int_as_float(p0.y));
    fma8(aB, g1, __int_as_float(p1.y));
    e += 2;
  }
  if (e < e1) {
    const int2 p0 = cpk[e];
    const uint4 g0 = s8[(size_t)p0.x * 8 + lane];
    fma8(aC, g0, __int_as_float(p0.y));
  }
  float p = 0.f;
#pragma unroll
  for (int j = 0; j < 8; ++j) p += expf((aA[j] + aB[j]) + (aC[j] + aD[j]));
#pragma unroll
  for (int off = 4; off > 0; off >>= 1) p += __shfl_down(p, off, 8);
  __shared__ float part[32];
  if (lane == 0) part[tid >> 3] = p;
  __syncthreads();
  if (tid == 0) {
    float s = 0.f;
#pragma unroll
    for (int i = 0; i < 32; ++i) s += part[i];
    pexp[blockIdx.x] = s;
  }
}

// ---------------- finalize ----------------
__global__ __launch_bounds__(256) void k_final(const float* __restrict__ pzmu, int nz,
                                               const float* __restrict__ pexp, int ne,
                                               float* __restrict__ out) {
  __shared__ float red[256];
  const int t = threadIdx.x;
  float s1 = 0.f, s2 = 0.f;
  for (int i = t; i < nz; i += 256) s1 += pzmu[i];
  for (int i = t; i < ne; i += 256) s2 += pexp[i];
  red[t] = s1;
  __syncthreads();
  for (int off = 128; off > 0; off >>= 1) {
    if (t < off) red[t] += red[t + off];
    __syncthreads();
  }
  const float tot1 = red[0];
  __syncthreads();
  red[t] = s2;
  __syncthreads();
  for (int off = 128; off > 0; off >>= 1) {
    if (t < off) red[t] += red[t + off];
    __syncthreads();
  }
  if (t == 0) {
    const float denom = (float)NN * (float)DO;  // mean over [N, 64]
    out[0] = tot1 / denom;
    out[1] = logf(red[0] / denom);
  }
}

}  // namespace

extern "C" void kernel_launch(void* const* d_in, const int* in_sizes, int n_in,
                              void* d_out, int out_size, void* d_ws, size_t ws_size,
                              hipStream_t stream) {
  const float* x    = (const float*)d_in[0];
  const int*   erow = (const int*)d_in[1];
  const int*   ecol = (const int*)d_in[2];
  const float* eval = (const float*)d_in[3];
  const float* W1   = (const float*)d_in[4];
  const float* W2   = (const float*)d_in[5];
  const float* W3   = (const float*)d_in[6];
  float* out = (float*)d_out;

  // workspace carve-out (256B aligned); peak ~85 MB
  char* p = (char*)d_ws;
  auto alloc = [&](size_t bytes) -> void* {
    void* r = (void*)p;
    p += (bytes + 255) & ~(size_t)255;
    return r;
  };
  unsigned short* sup = (unsigned short*)alloc((size_t)NN * DH * 2);  // support1; reused as support3
  unsigned short* h1  = (unsigned short*)alloc((size_t)NN * DH * 2);  // h1 bf16
  int2*  cpk    = (int2*)alloc((size_t)NE * 8);   // final CSR (col, valbits)
  uint2* scv    = (uint2*)alloc((size_t)NE * 8);  // bucket-sorted (low8|col, valbits)
  unsigned short* rank8 = (unsigned short*)alloc((size_t)NE * 2);
  int*   rowptr = (int*)alloc((size_t)(NN + 1) * 4);
  int*   gcnt   = (int*)alloc((size_t)NBA * NBUK * 4);  // [block][bucket]
  int*   boff   = (int*)alloc((size_t)NBUK * NBA * 4);  // [bucket][block]
  int*   btot   = (int*)alloc((size_t)NBUK * 4);
  int*   bbase  = (int*)alloc((size_t)(NBUK + 1) * 4);
  float* hw     = (float*)alloc((size_t)NN * 4);
  float* w2s    = (float*)alloc(DH * 4);
  unsigned short* w1t = (unsigned short*)alloc((size_t)DH * DI * 2);  // W1^T bf16 [128][256]
  unsigned short* w3t = (unsigned short*)alloc((size_t)DO * DH * 2);  // W3^T bf16 [64][128]
  float* pexp   = (float*)alloc(SP3_NB * 4);
  float* pzmu   = (float*)alloc(EDOT_NB * 4);

  // weight prep first (GEMM1 consumes w1t)
  k_prep<<<PREP_NB, 256, 0, stream>>>(W1, W3, w1t, w3t);

  // CSR build, LDS-atomics only
  k_passA<<<NBA, 256, 0, stream>>>(erow, gcnt, rank8);
  k_passB1<<<NBUK, 256, 0, stream>>>(gcnt, boff, btot);
  k_passB2<<<2, 256, 0, stream>>>(btot, bbase, rowptr, W2, w2s);
  // GEMM1 (support1 = x@W1, BK=64 LDS) fused with bucket placement
  k_cg1<<<G1_NB + NBA, 256, 0, stream>>>(x, w1t, sup, erow, ecol, eval,
                                         rank8, boff, bbase, scv);
  // per-bucket counting sort -> cpk + rowptr
  k_passD<<<NBUK, 256, 0, stream>>>(scv, bbase, rowptr, cpk);

  // h1 = relu(spmm(support1)) [bf16]; hw = h1 . w2sum   (mu branch folded)
  k_spmm1<<<NN / 16, 256, 0, stream>>>(sup, rowptr, cpk, w2s, h1, hw);

  // fused: GEMM2 (support3 = h1@W3, MFMA) + z_mu edge-dot partials
  k_g2_edot<<<G1_NB * 9, 256, 0, stream>>>(h1, w3t, sup, ecol, eval, hw, pzmu);

  // logvar spmm fused with sum(exp(.)) -> per-block partials
  k_spmm3<<<NN / 32, 256, 0, stream>>>(sup, rowptr, cpk, pexp);

  k_final<<<1, 256, 0, stream>>>(pzmu, EDOT_NB, pexp, SP3_NB, out);
}